// Round 12
// baseline (61.947 us; speedup 1.0000x reference)
//
#include <hip/hip_runtime.h>
#include <hip/hip_bf16.h>

// Problem constants (from reference setup_inputs)
#define T1 4095     // existing stack entries
#define TT 4096     // T1 + 1
#define B  64
#define M  128
#define BM (B * M)                // 8192
#define ROW4 (BM / 4)             // 2048 float4 per row
#define SCAN_THREADS 1024
#define NWAVE (SCAN_THREADS / 64) // 16 waves
#define EPT (TT / SCAN_THREADS)   // 4 elements per thread in scan
#define IPB 64                    // rows per fuse chunk (was 32)
#define HPB (IPB / 2)             // 32 rows per half-block
#define SUB 16                    // rows per coeff sub-batch
#define NCHUNK (TT / IPB)         // 64

typedef float f32x4 __attribute__((ext_vector_type(4)));

// Kernel 1: per batch b (one block per b), 1024 threads (16 waves):
//   sn[i] = relu(s[i] - relu(u - suffix_s[i])), sn[T1] = d
//   coeff[i] = min(sn[i], relu(1 - suffix_sn[i]))
// sn -> output layout [TT,B]; coeff -> TRANSPOSED [B,TT] for coalesced reuse.
__global__ __launch_bounds__(SCAN_THREADS) void scan_kernel(
    const float* __restrict__ s,    // [T1, B]
    const float* __restrict__ d,    // [B]
    const float* __restrict__ u,    // [B]
    float* __restrict__ sn_out,     // [TT, B]  (output 1)
    float* __restrict__ coeffT)     // [B, TT]  (workspace, transposed)
{
    const int b = blockIdx.x;
    const int t = threadIdx.x;
    const int lane = t & 63;
    const int wave = t >> 6;        // 0..15
    __shared__ float wtot1[NWAVE];
    __shared__ float wtot2[NWAVE];

    const int base = t * EPT;
    float sv[EPT];
    float sum = 0.f;
#pragma unroll
    for (int k = 0; k < EPT; ++k) {
        int i = base + k;
        float val = (i < T1) ? s[(size_t)i * B + b] : 0.f;
        sv[k] = val;
        sum += val;
    }

    // Wave-level inclusive suffix scan (Kogge-Stone, high-to-low).
    float x = sum;
#pragma unroll
    for (int off = 1; off < 64; off <<= 1) {
        float y = __shfl_down(x, off);
        if (lane + off < 64) x += y;
    }
    if (lane == 0) wtot1[wave] = x;          // wave total
    __syncthreads();
    float after = 0.f;
#pragma unroll
    for (int w = 0; w < NWAVE; ++w)
        if (w > wave) after += wtot1[w];
    float suffix = after + x - sum;          // exclusive suffix for this thread

    const float ub = u[b];
    float tot = suffix;
    float snv[EPT];
#pragma unroll
    for (int k = EPT - 1; k >= 0; --k) {
        float sval = sv[k];
        snv[k] = fmaxf(sval - fmaxf(ub - tot, 0.f), 0.f);
        tot += sval;
    }
    if (t == SCAN_THREADS - 1) snv[EPT - 1] = d[b];  // element T1: sn = d

    float sum2 = 0.f;
#pragma unroll
    for (int k = 0; k < EPT; ++k) sum2 += snv[k];
    float x2 = sum2;
#pragma unroll
    for (int off = 1; off < 64; off <<= 1) {
        float y = __shfl_down(x2, off);
        if (lane + off < 64) x2 += y;
    }
    if (lane == 0) wtot2[wave] = x2;
    __syncthreads();
    float after2 = 0.f;
#pragma unroll
    for (int w = 0; w < NWAVE; ++w)
        if (w > wave) after2 += wtot2[w];
    float suffix2 = after2 + x2 - sum2;

    float tot2 = suffix2;
    float cv[EPT];
#pragma unroll
    for (int k = EPT - 1; k >= 0; --k) {
        float snval = snv[k];
        cv[k] = fminf(snval, fmaxf(1.f - tot2, 0.f));
        tot2 += snval;
        sn_out[(size_t)(base + k) * B + b] = snval;
    }
    f32x4 cc = { cv[0], cv[1], cv[2], cv[3] };
    *(f32x4*)(coeffT + (size_t)b * TT + base) = cc;   // coalesced float4
}

// Kernel 2: fused Vn copy + coeff-weighted partial reduction.
// Strip layout, 512-thread blocks, IPB=64 (was 32): grid (8 bmTiles, 64
// chunks) = 512 blocks, 2/CU. Each half-thread streams 32 rows (two 16-row
// coeff sub-batches) -> 2x longer steady-state per block, half the partials.
// Cached V loads (L3 reuse across replays); NT stores (A/B-proven).
__global__ __launch_bounds__(512) void fuse_kernel(
    const float* __restrict__ V,        // [T1, B, M]
    const float* __restrict__ v,        // [B, M]
    const float* __restrict__ coeffT,   // [B, TT]
    float* __restrict__ Vn,             // [TT, B, M] (output 0)
    float* __restrict__ partials)       // [NCHUNK, BM]
{
    const int bmTile = blockIdx.x;                   // 0..7
    const int chunk  = blockIdx.y;                   // 0..NCHUNK-1
    const int tid  = threadIdx.x;                    // 0..511
    const int half = tid >> 8;                       // 0 or 1
    const int t    = tid & 255;
    const int bm4  = bmTile * 256 + t;               // float4 column
    const int b    = bm4 >> 5;                       // batch (32 f4 per batch)
    const int i0   = chunk * IPB + half * HPB;       // 32 rows per half

    const float* cbase = coeffT + (size_t)b * TT;
    const f32x4* Vp  = (const f32x4*)V;
    f32x4*       Vnp = (f32x4*)Vn;

    f32x4 acc = {0.f, 0.f, 0.f, 0.f};
    const bool lastHalf = (chunk == NCHUNK - 1) && (half == 1);

#pragma unroll
    for (int sub = 0; sub < HPB / SUB; ++sub) {
        const int rbase = i0 + sub * SUB;
        const bool lastSub = lastHalf && (sub == HPB / SUB - 1);

        // Preload this sub-batch's 16 coefficients (contiguous, L2-hot).
        float c[SUB];
        const f32x4* cp = (const f32x4*)(cbase + rbase);
#pragma unroll
        for (int q = 0; q < SUB / 4; ++q) {
            f32x4 cc = cp[q];
            c[4*q+0] = cc.x; c[4*q+1] = cc.y; c[4*q+2] = cc.z; c[4*q+3] = cc.w;
        }

        if (!lastSub) {
#pragma unroll
            for (int k = 0; k < SUB; ++k) {
                const size_t idx = (size_t)(rbase + k) * ROW4 + bm4;
                f32x4 val = Vp[idx];                   // cached read (L3 reuse)
                __builtin_nontemporal_store(val, &Vnp[idx]);
                acc += c[k] * val;
            }
        } else {
#pragma unroll
            for (int k = 0; k < SUB - 1; ++k) {
                const size_t idx = (size_t)(rbase + k) * ROW4 + bm4;
                f32x4 val = Vp[idx];
                __builtin_nontemporal_store(val, &Vnp[idx]);
                acc += c[k] * val;
            }
            f32x4 val = ((const f32x4*)v)[bm4];        // push v at i = T1
            __builtin_nontemporal_store(val, &Vnp[(size_t)T1 * ROW4 + bm4]);
            acc += c[SUB - 1] * val;
        }
    }

    // Combine the two halves (4 KB LDS, one barrier), then store partial.
    __shared__ f32x4 sh[256];
    if (half == 1) sh[t] = acc;
    __syncthreads();
    if (half == 0)
        ((f32x4*)partials)[(size_t)chunk * ROW4 + bm4] = acc + sh[t];
}

// Kernel 3: deterministic two-level reduction of partials -> r.
// 64 blocks x 256 threads; 8 chunk-groups x 32 float4 outputs per block.
__global__ __launch_bounds__(256) void reduce_kernel(
    const float* __restrict__ partials,  // [NCHUNK, BM]
    float* __restrict__ r)               // [B, M] (output 2)
{
    const int blk = blockIdx.x;          // 0..63
    const int tid = threadIdx.x;
    const int grp = tid >> 5;            // 0..7
    const int lane = tid & 31;
    const int out4 = blk * 32 + lane;    // float4 output index 0..2047

    f32x4 acc = {0.f, 0.f, 0.f, 0.f};
#pragma unroll
    for (int c = grp; c < NCHUNK; c += 8)
        acc += ((const f32x4*)partials)[(size_t)c * ROW4 + out4];

    __shared__ f32x4 sh[256];
    sh[tid] = acc;
    __syncthreads();
    if (tid < 128) sh[tid] += sh[tid + 128];
    __syncthreads();
    if (tid < 64) sh[tid] += sh[tid + 64];
    __syncthreads();
    if (tid < 32) {
        f32x4 res = sh[tid] + sh[tid + 32];
        ((f32x4*)r)[out4] = res;
    }
}

extern "C" void kernel_launch(void* const* d_in, const int* in_sizes, int n_in,
                              void* d_out, int out_size, void* d_ws, size_t ws_size,
                              hipStream_t stream) {
    const float* V = (const float*)d_in[0];   // [T1,B,M]
    const float* s = (const float*)d_in[1];   // [T1,B,1]
    const float* d = (const float*)d_in[2];   // [B,1]
    const float* u = (const float*)d_in[3];   // [B,1]
    const float* v = (const float*)d_in[4];   // [B,M]

    float* out = (float*)d_out;
    float* Vn = out;                                   // TT*B*M
    float* sn = out + (size_t)TT * BM;                 // TT*B
    float* r  = sn + (size_t)TT * B;                   // B*M

    float* coeffT   = (float*)d_ws;                    // B*TT floats (1 MB)
    float* partials = coeffT + (size_t)B * TT;         // NCHUNK*BM floats (2 MB)

    scan_kernel<<<B, SCAN_THREADS, 0, stream>>>(s, d, u, sn, coeffT);
    fuse_kernel<<<dim3(8, NCHUNK), 512, 0, stream>>>(V, v, coeffT, Vn, partials);
    reduce_kernel<<<64, 256, 0, stream>>>(partials, r);
}

// Round 13
// 56.376 us; speedup vs baseline: 1.0988x; 1.0988x over previous
//
#include <hip/hip_runtime.h>
#include <hip/hip_bf16.h>

// Problem constants (from reference setup_inputs)
#define T1 4095     // existing stack entries
#define TT 4096     // T1 + 1
#define B  64
#define M  128
#define BM (B * M)                // 8192
#define ROW4 (BM / 4)             // 2048 float4 per row
#define SCAN_THREADS 1024
#define NWAVE (SCAN_THREADS / 64) // 16 waves
#define EPT (TT / SCAN_THREADS)   // 4 elements per thread in scan
#define IPB 32                    // rows per fuse chunk
#define HPB (IPB / 2)             // 16 rows per half-block
#define NCHUNK (TT / IPB)         // 128

typedef float f32x4 __attribute__((ext_vector_type(4)));

// Kernel 1: per batch b (one block per b), 1024 threads (16 waves):
//   sn[i] = relu(s[i] - relu(u - suffix_s[i])), sn[T1] = d
//   coeff[i] = min(sn[i], relu(1 - suffix_sn[i]))
// BOTH outputs written TRANSPOSED [B,TT] (fully coalesced float4) — the
// strided [TT,B] sn write was the last scattered-write pattern (4B stores,
// 256B stride, cross-XCD partial lines -> HBM RMW). finish_kernel
// transposes snT into the required output layout.
__global__ __launch_bounds__(SCAN_THREADS) void scan_kernel(
    const float* __restrict__ s,    // [T1, B]
    const float* __restrict__ d,    // [B]
    const float* __restrict__ u,    // [B]
    float* __restrict__ snT,        // [B, TT]  (workspace, transposed)
    float* __restrict__ coeffT)     // [B, TT]  (workspace, transposed)
{
    const int b = blockIdx.x;
    const int t = threadIdx.x;
    const int lane = t & 63;
    const int wave = t >> 6;        // 0..15
    __shared__ float wtot1[NWAVE];
    __shared__ float wtot2[NWAVE];

    const int base = t * EPT;
    float sv[EPT];
    float sum = 0.f;
#pragma unroll
    for (int k = 0; k < EPT; ++k) {
        int i = base + k;
        float val = (i < T1) ? s[(size_t)i * B + b] : 0.f;
        sv[k] = val;
        sum += val;
    }

    // Wave-level inclusive suffix scan (Kogge-Stone, high-to-low).
    float x = sum;
#pragma unroll
    for (int off = 1; off < 64; off <<= 1) {
        float y = __shfl_down(x, off);
        if (lane + off < 64) x += y;
    }
    if (lane == 0) wtot1[wave] = x;          // wave total
    __syncthreads();
    float after = 0.f;
#pragma unroll
    for (int w = 0; w < NWAVE; ++w)
        if (w > wave) after += wtot1[w];
    float suffix = after + x - sum;          // exclusive suffix for this thread

    const float ub = u[b];
    float tot = suffix;
    float snv[EPT];
#pragma unroll
    for (int k = EPT - 1; k >= 0; --k) {
        float sval = sv[k];
        snv[k] = fmaxf(sval - fmaxf(ub - tot, 0.f), 0.f);
        tot += sval;
    }
    if (t == SCAN_THREADS - 1) snv[EPT - 1] = d[b];  // element T1: sn = d

    float sum2 = 0.f;
#pragma unroll
    for (int k = 0; k < EPT; ++k) sum2 += snv[k];
    float x2 = sum2;
#pragma unroll
    for (int off = 1; off < 64; off <<= 1) {
        float y = __shfl_down(x2, off);
        if (lane + off < 64) x2 += y;
    }
    if (lane == 0) wtot2[wave] = x2;
    __syncthreads();
    float after2 = 0.f;
#pragma unroll
    for (int w = 0; w < NWAVE; ++w)
        if (w > wave) after2 += wtot2[w];
    float suffix2 = after2 + x2 - sum2;

    float tot2 = suffix2;
    float cv[EPT];
#pragma unroll
    for (int k = EPT - 1; k >= 0; --k) {
        float snval = snv[k];
        cv[k] = fminf(snval, fmaxf(1.f - tot2, 0.f));
        tot2 += snval;
    }
    f32x4 sv4 = { snv[0], snv[1], snv[2], snv[3] };
    *(f32x4*)(snT + (size_t)b * TT + base) = sv4;     // coalesced float4
    f32x4 cc = { cv[0], cv[1], cv[2], cv[3] };
    *(f32x4*)(coeffT + (size_t)b * TT + base) = cc;   // coalesced float4
}

// Kernel 2: fused Vn copy + coeff-weighted partial reduction.
// Round-11 config (best measured, 59.5 us): strip layout (8 bmTiles, 128
// chunks), 512-thread blocks (32 waves/CU); half 0 -> rows [i0,i0+16),
// half 1 -> [i0+16,i0+32); halves combined via LDS. Cached V loads (L3
// reuse across replays); NT stores for Vn (A/B-proven vs plain).
__global__ __launch_bounds__(512) void fuse_kernel(
    const float* __restrict__ V,        // [T1, B, M]
    const float* __restrict__ v,        // [B, M]
    const float* __restrict__ coeffT,   // [B, TT]
    float* __restrict__ Vn,             // [TT, B, M] (output 0)
    float* __restrict__ partials)       // [NCHUNK, BM]
{
    const int bmTile = blockIdx.x;                   // 0..7
    const int chunk  = blockIdx.y;                   // 0..127
    const int tid  = threadIdx.x;                    // 0..511
    const int half = tid >> 8;                       // 0 or 1
    const int t    = tid & 255;
    const int bm4  = bmTile * 256 + t;               // float4 column
    const int b    = bm4 >> 5;                       // batch (32 f4 per batch)
    const int i0   = chunk * IPB + half * HPB;       // 16 rows per half

    // Preload this half's 16 coefficients (contiguous in coeffT).
    float c[HPB];
    const f32x4* cp = (const f32x4*)(coeffT + (size_t)b * TT + i0);
#pragma unroll
    for (int q = 0; q < HPB / 4; ++q) {
        f32x4 cc = cp[q];
        c[4*q+0] = cc.x; c[4*q+1] = cc.y; c[4*q+2] = cc.z; c[4*q+3] = cc.w;
    }

    f32x4 acc = {0.f, 0.f, 0.f, 0.f};
    const f32x4* Vp  = (const f32x4*)V;
    f32x4*       Vnp = (f32x4*)Vn;

    const bool lastHalf = (chunk == NCHUNK - 1) && (half == 1);
    if (!lastHalf) {
#pragma unroll
        for (int k = 0; k < HPB; ++k) {
            const size_t idx = (size_t)(i0 + k) * ROW4 + bm4;
            f32x4 val = Vp[idx];                       // cached read (L3 reuse)
            __builtin_nontemporal_store(val, &Vnp[idx]);
            acc += c[k] * val;
        }
    } else {
#pragma unroll
        for (int k = 0; k < HPB - 1; ++k) {
            const size_t idx = (size_t)(i0 + k) * ROW4 + bm4;
            f32x4 val = Vp[idx];
            __builtin_nontemporal_store(val, &Vnp[idx]);
            acc += c[k] * val;
        }
        f32x4 val = ((const f32x4*)v)[bm4];            // push v at i = T1
        __builtin_nontemporal_store(val, &Vnp[(size_t)T1 * ROW4 + bm4]);
        acc += c[HPB - 1] * val;
    }

    // Combine the two halves (4 KB LDS, one barrier), then store partial.
    __shared__ f32x4 sh[256];
    if (half == 1) sh[t] = acc;
    __syncthreads();
    if (half == 0)
        ((f32x4*)partials)[(size_t)chunk * ROW4 + bm4] = acc + sh[t];
}

// Kernel 3 (merged finish): blocks 0..63 reduce partials -> r (unchanged
// round-11 reduce); blocks 64..127 transpose snT [B,TT] -> sn [TT,B] via
// LDS tile (coalesced reads AND writes; full 256B lines per row).
__global__ __launch_bounds__(256) void finish_kernel(
    const float* __restrict__ partials,  // [NCHUNK, BM]
    const float* __restrict__ snT,       // [B, TT]
    float* __restrict__ r,               // [B, M] (output 2)
    float* __restrict__ sn_out)          // [TT, B] (output 1)
{
    const int blk = blockIdx.x;
    const int tid = threadIdx.x;

    if (blk < 64) {
        // ---- reduce ----
        const int grp = tid >> 5;            // 0..7
        const int lane = tid & 31;
        const int out4 = blk * 32 + lane;    // float4 output index 0..2047

        f32x4 acc = {0.f, 0.f, 0.f, 0.f};
#pragma unroll 8
        for (int c = grp; c < NCHUNK; c += 8)
            acc += ((const f32x4*)partials)[(size_t)c * ROW4 + out4];

        __shared__ f32x4 sh[256];
        sh[tid] = acc;
        __syncthreads();
        if (tid < 128) sh[tid] += sh[tid + 128];
        __syncthreads();
        if (tid < 64) sh[tid] += sh[tid + 64];
        __syncthreads();
        if (tid < 32) {
            f32x4 res = sh[tid] + sh[tid + 32];
            ((f32x4*)r)[out4] = res;
        }
    } else {
        // ---- transpose snT -> sn_out, 64 i-rows per block ----
        const int g = blk - 64;              // 0..63; rows [g*64, g*64+64)
        __shared__ float tile[64][65];       // +1 pad vs bank conflicts

        const int b  = tid >> 2;             // 0..63
        const int iq = tid & 3;              // 0..3 (16 i's each)
        const f32x4* src4 = (const f32x4*)(snT + (size_t)b * TT + g * 64 + iq * 16);
#pragma unroll
        for (int q = 0; q < 4; ++q) {
            f32x4 vv = src4[q];              // coalesced read
            tile[iq * 16 + q * 4 + 0][b] = vv.x;
            tile[iq * 16 + q * 4 + 1][b] = vv.y;
            tile[iq * 16 + q * 4 + 2][b] = vv.z;
            tile[iq * 16 + q * 4 + 3][b] = vv.w;
        }
        __syncthreads();

        const int il = tid >> 6;             // 0..3
        const int bb = tid & 63;             // 0..63
#pragma unroll
        for (int p = 0; p < 16; ++p) {
            const int i = p * 4 + il;
            sn_out[(size_t)(g * 64 + i) * B + bb] = tile[i][bb];  // full-line write
        }
    }
}

extern "C" void kernel_launch(void* const* d_in, const int* in_sizes, int n_in,
                              void* d_out, int out_size, void* d_ws, size_t ws_size,
                              hipStream_t stream) {
    const float* V = (const float*)d_in[0];   // [T1,B,M]
    const float* s = (const float*)d_in[1];   // [T1,B,1]
    const float* d = (const float*)d_in[2];   // [B,1]
    const float* u = (const float*)d_in[3];   // [B,1]
    const float* v = (const float*)d_in[4];   // [B,M]

    float* out = (float*)d_out;
    float* Vn = out;                                   // TT*B*M
    float* sn = out + (size_t)TT * BM;                 // TT*B
    float* r  = sn + (size_t)TT * B;                   // B*M

    float* coeffT   = (float*)d_ws;                    // B*TT floats (1 MB)
    float* snT      = coeffT + (size_t)B * TT;         // B*TT floats (1 MB)
    float* partials = snT + (size_t)B * TT;            // NCHUNK*BM floats (4 MB)

    scan_kernel<<<B, SCAN_THREADS, 0, stream>>>(s, d, u, snT, coeffT);
    fuse_kernel<<<dim3(8, NCHUNK), 512, 0, stream>>>(V, v, coeffT, Vn, partials);
    finish_kernel<<<128, 256, 0, stream>>>(partials, snT, r, sn);
}